// Round 2
// baseline (162.004 us; speedup 1.0000x reference)
//
#include <hip/hip_runtime.h>
#include <hip/hip_bf16.h>
#include <math.h>

// InfiniteContextAttention — causal mask makes only keys 0..15 (= compressed_k/v[:, :, :16])
// reachable. Pipeline: q = hidden @ Wq^T -> 16-key causal attention -> out = attn @ Wo^T.
//
// GEMM v2: 256 blocks x 256 thr. Block owns 16 cols, wave owns 4 cols.
// Rows split across half-waves (lanes 0-31: rows 0-15, lanes 32-63: rows 16-31),
// K split across 32 lanes (float4 each). Double-buffered LDS A-chunks (256 K),
// reg-staged A prefetch + W reg prefetch one chunk ahead (even/odd ping-pong).
// LDS traffic: 1024 waves x 512 KB = 512 MB (~10 us), HBM: 64 MB W (~10 us) — overlapped.

#define HID 4096
#define NROW 32
#define CHUNK 256
#define NCHUNK 16

#define DOT8(a0, a1, w0, w1) \
    (a0.x*w0.x + a0.y*w0.y + a0.z*w0.z + a0.w*w0.w + \
     a1.x*w1.x + a1.y*w1.y + a1.z*w1.z + a1.w*w1.w)

__global__ __launch_bounds__(256, 1)
void gemm32_kernel(const float* __restrict__ A,
                   const float* __restrict__ W,
                   float* __restrict__ C)
{
    __shared__ float As[2][NROW * CHUNK];  // 2 x 32 KB
    const int tid  = threadIdx.x;
    const int lane = tid & 63;
    const int wave = tid >> 6;        // 0..3
    const int kl   = lane & 31;       // K-lane within half-wave
    const int sub  = lane >> 5;       // row half: 0 -> rows 0-15, 1 -> rows 16-31
    const int r0   = sub << 4;
    const int j0   = blockIdx.x * 16 + wave * 4;

    // staging source: wave w stages rows w*8 .. w*8+7; lane covers float4 slot `lane`
    const float* ast = A + (size_t)(wave * 8) * HID + lane * 4;
    // W source: lane kl covers float4 slot kl of each 128-float pass
    const float* wp  = W + (size_t)j0 * HID + kl * 4;

    float acc[4][16];
#pragma unroll
    for (int c = 0; c < 4; ++c)
#pragma unroll
        for (int r = 0; r < 16; ++r) acc[c][r] = 0.f;

    float4 ga[8], wEv[8], wOd[8];

    // ---- prologue: chunk 0 A-regs + W-regs, write A chunk 0 to LDS buf 0 ----
#pragma unroll
    for (int i = 0; i < 8; ++i) ga[i] = *(const float4*)(ast + (size_t)i * HID);
#pragma unroll
    for (int c = 0; c < 4; ++c)
#pragma unroll
        for (int p = 0; p < 2; ++p)
            wEv[c * 2 + p] = *(const float4*)(wp + (size_t)c * HID + p * 128);
#pragma unroll
    for (int i = 0; i < 8; ++i)
        *(float4*)(&As[0][(wave * 8 + i) * CHUNK + lane * 4]) = ga[i];
    __syncthreads();

#define COMPUTE(BUF, WREG)                                                   \
    do {                                                                     \
        const float4* As4 = (const float4*)(As[BUF]);                        \
        _Pragma("unroll")                                                    \
        for (int rr = 0; rr < 16; ++rr) {                                    \
            float4 a0 = As4[(r0 + rr) * 64 + kl];                            \
            float4 a1 = As4[(r0 + rr) * 64 + 32 + kl];                       \
            _Pragma("unroll")                                                \
            for (int c = 0; c < 4; ++c)                                      \
                acc[c][rr] += DOT8(a0, a1, WREG[c * 2], WREG[c * 2 + 1]);    \
        }                                                                    \
    } while (0)

    for (int cc = 0; cc < NCHUNK; cc += 2) {
        // ---- even chunk cc: compute from buf0/wEv, prefetch cc+1 ----
        {
            const int kn = (cc + 1) * CHUNK;
#pragma unroll
            for (int i = 0; i < 8; ++i)
                ga[i] = *(const float4*)(ast + (size_t)i * HID + kn);
#pragma unroll
            for (int c = 0; c < 4; ++c)
#pragma unroll
                for (int p = 0; p < 2; ++p)
                    wOd[c * 2 + p] = *(const float4*)(wp + (size_t)c * HID + p * 128 + kn);
            COMPUTE(0, wEv);
#pragma unroll
            for (int i = 0; i < 8; ++i)
                *(float4*)(&As[1][(wave * 8 + i) * CHUNK + lane * 4]) = ga[i];
            __syncthreads();
        }
        // ---- odd chunk cc+1: compute from buf1/wOd, prefetch cc+2 ----
        {
            const bool more = (cc + 2) < NCHUNK;
            if (more) {
                const int kn = (cc + 2) * CHUNK;
#pragma unroll
                for (int i = 0; i < 8; ++i)
                    ga[i] = *(const float4*)(ast + (size_t)i * HID + kn);
#pragma unroll
                for (int c = 0; c < 4; ++c)
#pragma unroll
                    for (int p = 0; p < 2; ++p)
                        wEv[c * 2 + p] = *(const float4*)(wp + (size_t)c * HID + p * 128 + kn);
            }
            COMPUTE(1, wOd);
            if (more) {
#pragma unroll
                for (int i = 0; i < 8; ++i)
                    *(float4*)(&As[0][(wave * 8 + i) * CHUNK + lane * 4]) = ga[i];
            }
            __syncthreads();
        }
    }

    // ---- reduce over 32 K-lanes within each half-wave ----
#pragma unroll
    for (int m = 1; m <= 16; m <<= 1)
#pragma unroll
        for (int c = 0; c < 4; ++c)
#pragma unroll
            for (int rr = 0; rr < 16; ++rr)
                acc[c][rr] += __shfl_xor(acc[c][rr], m, 64);

    // ---- store: lane kl owns (rr = kl&15, c&1 = kl>>4), two cols each ----
#pragma unroll
    for (int c = 0; c < 4; ++c)
#pragma unroll
        for (int rr = 0; rr < 16; ++rr)
            if (kl == (rr | ((c & 1) << 4)))
                C[(size_t)(r0 + rr) * HID + j0 + c] = acc[c][rr];
}

// One wave per (b, h, i): 16-key causal attention over compressed_k/v[:, :, :16].
// Lane l owns head-dims {2l, 2l+1}. In-place safe (read-before-write per lane).
__global__ __launch_bounds__(256)
void attn16_kernel(const float* __restrict__ q,
                   const float* __restrict__ ck,
                   const float* __restrict__ cv,
                   float* __restrict__ o)
{
    const int lane = threadIdx.x & 63;
    const int g = blockIdx.x * 4 + (threadIdx.x >> 6);  // 0..1023
    const int b = g >> 9;
    const int h = (g >> 4) & 31;
    const int i = g & 15;

    const size_t qoff = ((size_t)(b * 16 + i)) * HID + h * 128 + 2 * lane;
    const float2 q2 = *(const float2*)(q + qoff);
    const size_t kvoff = ((size_t)(b * 32 + h)) * 2048 * 128 + 2 * lane;
    const float* kp = ck + kvoff;
    const float* vp = cv + kvoff;

    float e[16];
#pragma unroll
    for (int s = 0; s < 16; ++s) {
        float2 k2 = *(const float2*)(kp + (size_t)s * 128);
        float p = q2.x * k2.x + q2.y * k2.y;
#pragma unroll
        for (int m = 32; m >= 1; m >>= 1) p += __shfl_xor(p, m, 64);
        e[s] = (s <= i) ? p * 0.08838834764831845f : -3.4e38f;  // i wave-uniform
    }
    float mx = e[0];
#pragma unroll
    for (int s = 1; s < 16; ++s) mx = fmaxf(mx, e[s]);
    float den = 0.f;
#pragma unroll
    for (int s = 0; s < 16; ++s) { e[s] = __expf(e[s] - mx); den += e[s]; }
    const float inv = 1.0f / den;

    float ox = 0.f, oy = 0.f;
#pragma unroll
    for (int s = 0; s < 16; ++s) {
        float2 v2 = *(const float2*)(vp + (size_t)s * 128);
        ox += e[s] * v2.x;
        oy += e[s] * v2.y;
    }
    float2 res;
    res.x = ox * inv;
    res.y = oy * inv;
    *(float2*)(o + qoff) = res;
}

extern "C" void kernel_launch(void* const* d_in, const int* in_sizes, int n_in,
                              void* d_out, int out_size, void* d_ws, size_t ws_size,
                              hipStream_t stream) {
    const float* hidden = (const float*)d_in[0];  // [2][16][4096]
    const float* ck     = (const float*)d_in[3];  // [2][32][2048][128]
    const float* cv     = (const float*)d_in[4];
    const float* Wq     = (const float*)d_in[5];  // [4096][4096]
    const float* Wo     = (const float*)d_in[8];
    float* out = (float*)d_out;                   // [2][16][4096]
    float* q   = (float*)d_ws;                    // 512 KB scratch: q / attn (in-place)

    hipLaunchKernelGGL(gemm32_kernel, dim3(256), dim3(256), 0, stream, hidden, Wq, q);
    hipLaunchKernelGGL(attn16_kernel, dim3(256), dim3(256), 0, stream, q, ck, cv, q);
    hipLaunchKernelGGL(gemm32_kernel, dim3(256), dim3(256), 0, stream, q, Wo, out);
}

// Round 3
// 37.445 us; speedup vs baseline: 4.3265x; 4.3265x over previous
//
#include <hip/hip_runtime.h>
#include <math.h>

// InfiniteContextAttention — causal mask reaches only keys 0..15 (= compressed_k/v[:,:, :16]).
// Pipeline: q = hidden @ Wq^T -> 16-key causal attention -> out = attn @ Wo^T.
//
// GEMM v3 (MFMA bf16): C[32][4096] = A[32][4096] @ W[4096][4096]^T.
// 512 blocks = 64 col-groups x 8 K-slices; block = 4 waves = 64 cols, K-slice 512.
// A-slice staged once -> bf16 swizzled LDS (32 KB, one barrier). W streamed
// global->reg->bf16->MFMA (no LDS, no barriers in K-loop -> compiler pipelines).
// Partials [8][32][4096]; q-reduce fused into attn; final reduce kernel for out.

#define HID 4096
#define NROW 32
#define NSLICE 8
#define KSL 512
#define PART_STRIDE (NROW * HID)  // 131072 floats per slice

typedef __attribute__((ext_vector_type(8))) short short8;
typedef __attribute__((ext_vector_type(4))) float f32x4;

__device__ __forceinline__ unsigned short bf16_rne(float x) {
    union { float f; unsigned u; } c; c.f = x;
    unsigned u = c.u;
    return (unsigned short)((u + 0x7fffu + ((u >> 16) & 1u)) >> 16);
}

__global__ __launch_bounds__(256, 2)
void gemm_mfma(const float* __restrict__ A,   // [32][4096] fp32
               const float* __restrict__ W,   // [4096][4096] fp32
               float* __restrict__ P)         // [8][32][4096] fp32 partials
{
    __shared__ short As[NROW * KSL];  // 32 KB bf16, XOR-swizzled (T2)
    const int tid  = threadIdx.x;
    const int lane = tid & 63;
    const int wv   = tid >> 6;            // wave 0..3 -> 16-col tile
    const int cg   = blockIdx.x & 63;     // column group (64 cols)
    const int sl   = blockIdx.x >> 6;     // K-slice 0..7
    const int ks   = sl * KSL;

    // ---- stage A slice (fp32 -> bf16, swizzled), coalesced 128B-granule reads ----
    {
        const int r  = tid >> 3;          // row 0..31
        const int c8 = tid & 7;           // float4 column subgroup
        const float* src = A + (size_t)r * HID + ks + c8 * 4;
        char* lb = (char*)As + r * (KSL * 2);
        const int rx = (r & 7) << 4;
#pragma unroll
        for (int i = 0; i < 16; ++i) {
            float4 v = *(const float4*)(src + i * 32);
            unsigned long long pk =
                  (unsigned long long)bf16_rne(v.x)
                | ((unsigned long long)bf16_rne(v.y) << 16)
                | ((unsigned long long)bf16_rne(v.z) << 32)
                | ((unsigned long long)bf16_rne(v.w) << 48);
            int byte = ((c8 + 8 * i) * 8) ^ rx;
            *(unsigned long long*)(lb + byte) = pk;
        }
    }
    __syncthreads();  // the only barrier: LDS written once

    const int l15 = lane & 15, lq = lane >> 4, l7 = lane & 7;
    const int jcol = cg * 64 + wv * 16 + l15;
    const float* wp = W + (size_t)jcol * HID + ks + lq * 8;
    const char* lA0 = (const char*)As + l15 * (KSL * 2);
    const char* lA1 = (const char*)As + (16 + l15) * (KSL * 2);
    const int rswz = l7 << 4;

    f32x4 acc0 = {0.f, 0.f, 0.f, 0.f}, acc1 = {0.f, 0.f, 0.f, 0.f};
    float4 w0 = *(const float4*)(wp);
    float4 w1 = *(const float4*)(wp + 4);

#pragma unroll
    for (int kk = 0; kk < 16; ++kk) {
        float4 n0, n1;
        if (kk < 15) {  // prefetch next step's W (reg double-buffer, no barriers)
            n0 = *(const float4*)(wp + (kk + 1) * 32);
            n1 = *(const float4*)(wp + (kk + 1) * 32 + 4);
        }
        const int byte = ((kk * 64) + (lq * 16)) ^ rswz;
        short8 a0 = *(const short8*)(lA0 + byte);
        short8 a1 = *(const short8*)(lA1 + byte);
        short8 b;
        b[0] = (short)bf16_rne(w0.x); b[1] = (short)bf16_rne(w0.y);
        b[2] = (short)bf16_rne(w0.z); b[3] = (short)bf16_rne(w0.w);
        b[4] = (short)bf16_rne(w1.x); b[5] = (short)bf16_rne(w1.y);
        b[6] = (short)bf16_rne(w1.z); b[7] = (short)bf16_rne(w1.w);
        acc0 = __builtin_amdgcn_mfma_f32_16x16x32_bf16(a0, b, acc0, 0, 0, 0);
        acc1 = __builtin_amdgcn_mfma_f32_16x16x32_bf16(a1, b, acc1, 0, 0, 0);
        w0 = n0; w1 = n1;
    }

    // ---- epilogue: C/D layout col=lane&15, row=(lane>>4)*4+reg (m89-verified) ----
    float* pout = P + (size_t)sl * PART_STRIDE + jcol;
#pragma unroll
    for (int rr = 0; rr < 4; ++rr) {
        pout[(size_t)(lq * 4 + rr) * HID]        = acc0[rr];
        pout[(size_t)(16 + lq * 4 + rr) * HID]   = acc1[rr];
    }
}

// One wave per (b,h,i): fuses the 8-slice q-reduction with 16-key causal attention.
__global__ __launch_bounds__(256)
void attn16_kernel(const float* __restrict__ P,   // q partials [8][32][4096]
                   const float* __restrict__ ck,
                   const float* __restrict__ cv,
                   float* __restrict__ o)          // [32][4096]
{
    const int lane = threadIdx.x & 63;
    const int g = blockIdx.x * 4 + (threadIdx.x >> 6);  // 0..1023
    const int b = g >> 9;
    const int h = (g >> 4) & 31;
    const int i = g & 15;

    const size_t qoff = ((size_t)(b * 16 + i)) * HID + h * 128 + 2 * lane;
    float2 q2 = {0.f, 0.f};
#pragma unroll
    for (int s = 0; s < NSLICE; ++s) {
        float2 p = *(const float2*)(P + (size_t)s * PART_STRIDE + qoff);
        q2.x += p.x; q2.y += p.y;
    }
    const size_t kvoff = ((size_t)(b * 32 + h)) * 2048 * 128 + 2 * lane;
    const float* kp = ck + kvoff;
    const float* vp = cv + kvoff;

    float e[16];
#pragma unroll
    for (int s = 0; s < 16; ++s) {
        float2 k2 = *(const float2*)(kp + (size_t)s * 128);
        float p = q2.x * k2.x + q2.y * k2.y;
#pragma unroll
        for (int m = 32; m >= 1; m >>= 1) p += __shfl_xor(p, m, 64);
        e[s] = (s <= i) ? p * 0.08838834764831845f : -3.4e38f;  // i wave-uniform
    }
    float mx = e[0];
#pragma unroll
    for (int s = 1; s < 16; ++s) mx = fmaxf(mx, e[s]);
    float den = 0.f;
#pragma unroll
    for (int s = 0; s < 16; ++s) { e[s] = __expf(e[s] - mx); den += e[s]; }
    const float inv = 1.0f / den;

    float ox = 0.f, oy = 0.f;
#pragma unroll
    for (int s = 0; s < 16; ++s) {
        float2 v2 = *(const float2*)(vp + (size_t)s * 128);
        ox += e[s] * v2.x;
        oy += e[s] * v2.y;
    }
    float2 res; res.x = ox * inv; res.y = oy * inv;
    *(float2*)(o + qoff) = res;
}

// out[i] = sum over 8 slices of P[s][i]; 32768 float4s.
__global__ __launch_bounds__(256)
void reduce8_kernel(const float* __restrict__ P, float* __restrict__ out)
{
    const int idx = blockIdx.x * 256 + threadIdx.x;  // float4 index
    const float4* p4 = (const float4*)P;
    float4 s = p4[idx];
#pragma unroll
    for (int t = 1; t < NSLICE; ++t) {
        float4 v = p4[idx + t * (PART_STRIDE / 4)];
        s.x += v.x; s.y += v.y; s.z += v.z; s.w += v.w;
    }
    ((float4*)out)[idx] = s;
}

extern "C" void kernel_launch(void* const* d_in, const int* in_sizes, int n_in,
                              void* d_out, int out_size, void* d_ws, size_t ws_size,
                              hipStream_t stream) {
    const float* hidden = (const float*)d_in[0];  // [2][16][4096]
    const float* ck     = (const float*)d_in[3];  // [2][32][2048][128]
    const float* cv     = (const float*)d_in[4];
    const float* Wq     = (const float*)d_in[5];  // [4096][4096]
    const float* Wo     = (const float*)d_in[8];
    float* out  = (float*)d_out;                  // [2][16][4096]
    float* part = (float*)d_ws;                   // [8][32][4096] = 4 MB
    float* abuf = part + NSLICE * PART_STRIDE;    // [32][4096] attn output

    hipLaunchKernelGGL(gemm_mfma,     dim3(512), dim3(256), 0, stream, hidden, Wq, part);
    hipLaunchKernelGGL(attn16_kernel, dim3(256), dim3(256), 0, stream, part, ck, cv, abuf);
    hipLaunchKernelGGL(gemm_mfma,     dim3(512), dim3(256), 0, stream, abuf, Wo, part);
    hipLaunchKernelGGL(reduce8_kernel,dim3(128), dim3(256), 0, stream, part, out);
}